// Round 8
// baseline (529.296 us; speedup 1.0000x reference)
//
#include <hip/hip_runtime.h>

#define NUM_TASKS 8
#define NUM_TABLES 16
#define HASH 1000000
#define BATCH 8192
#define NNZ (BATCH * 20)
#define OFF_ROW (BATCH + 1)
#define NPASS 16
#define RANGE (HASH / NPASS)        // 62500
#define CHUNK 640
#define NCHUNK (NNZ / CHUNK)        // 256
#define SORT_STRIDE (NNZ + 512)

// ws layout (bytes). hist/bb/cbag live INSIDE the partial region but are dead
// before gather (the only writer of partial) runs — safe aliasing.
#define WS_PART  0ull                                   // [16p][16t][8192b][8task] f32 = 64 MB
#define WS_HIST  0ull                                   // [16t][16k][256c] u32 = 256 KB
#define WS_BB    262144ull                              // [16t][16k] u32
#define WS_CNTB  263168ull                              // [16t][16k] u32
#define WS_CBAG  (1ull << 20)                           // [16t][16k][8192b] u32 = 8 MB
#define PART_BYTES ((size_t)NPASS * NUM_TABLES * BATCH * NUM_TASKS * 4)   // 67,108,864
#define WS_RP    PART_BYTES                             // [16t][16k][8193] u32 = 8.39 MB
#define RP_BYTES ((size_t)NUM_TABLES * NPASS * (BATCH + 1) * 4)
#define WS_SORT  (WS_RP + RP_BYTES)                     // [16t][SORT_STRIDE] u32 = 10.5 MB
#define WS_NEED  (WS_SORT + (size_t)NUM_TABLES * SORT_STRIDE * 4)         // ~86 MB

// ---------- 1) per-chunk histogram + zero cbag ----------
__global__ void hist_kernel(const int* __restrict__ indices, unsigned* __restrict__ hist,
                            uint4* __restrict__ cbag_v)   // 524288 uint4 = 8 MB
{
    int zt = blockIdx.x * blockDim.x + threadIdx.x;
    uint4 z = make_uint4(0u, 0u, 0u, 0u);
    cbag_v[zt * 2]     = z;
    cbag_v[zt * 2 + 1] = z;

    __shared__ int h[4][NPASS];
    int w = threadIdx.x >> 6, lane = threadIdx.x & 63;
    int g = blockIdx.x * 4 + w;
    int t = g >> 8, chunk = g & 255;
    if (lane < NPASS) h[w][lane] = 0;
    __syncthreads();
    const int* ip = indices + (size_t)t * NNZ + chunk * CHUNK;
    for (int r = 0; r < CHUNK / 64; ++r) {
        int k = ip[r * 64 + lane] / RANGE;
        atomicAdd(&h[w][k], 1);
    }
    __syncthreads();
    if (lane < NPASS) hist[((size_t)t * NPASS + lane) * NCHUNK + chunk] = (unsigned)h[w][lane];
}

// ---------- 2) scan: per-(t,k) exclusive chunk scan + 32-aligned bucket bases ----------
__global__ void scan_kernel(unsigned* __restrict__ hist, unsigned* __restrict__ bb, unsigned* __restrict__ cnt)
{
    int t = blockIdx.x, tid = threadIdx.x;
    __shared__ unsigned tot[NPASS];
    if (tid < NPASS) {
        unsigned run = 0;
        unsigned* hp = hist + ((size_t)t * NPASS + tid) * NCHUNK;
        for (int c = 0; c < NCHUNK; ++c) { unsigned v = hp[c]; hp[c] = run; run += v; }
        tot[tid] = run;
        cnt[t * NPASS + tid] = run;
    }
    __syncthreads();
    if (tid == 0) {
        unsigned base = 0;
        for (int k = 0; k < NPASS; ++k) { bb[t * NPASS + k] = base; base += (tot[k] + 31u) & ~31u; }
    }
}

// ---------- 3) stable scatter + per-(t,k,bag) counts ----------
__global__ void scatter_kernel(const int* __restrict__ indices, const int* __restrict__ offsets,
                               const unsigned* __restrict__ hist, const unsigned* __restrict__ bb,
                               unsigned* __restrict__ sorted, unsigned* __restrict__ cbag)
{
    int w = threadIdx.x >> 6, lane = threadIdx.x & 63;
    int g = blockIdx.x * 4 + w;
    int t = g >> 8, chunk = g & 255;
    unsigned cur = 0;
    if (lane < NPASS)
        cur = bb[t * NPASS + lane] + hist[((size_t)t * NPASS + lane) * NCHUNK + chunk];
    unsigned long long mlt = (1ull << lane) - 1ull;
    const int* off = offsets + t * OFF_ROW;
    const int* ip  = indices + (size_t)t * NNZ;
    unsigned* sp   = sorted + (size_t)t * SORT_STRIDE;

    for (int r = 0; r < CHUNK / 64; ++r) {
        int i = chunk * CHUNK + r * 64 + lane;
        int raw = ip[i];
        int k   = raw / RANGE;
        int hlo = raw - k * RANGE;
        int lo = 0, hi = BATCH;                 // bag: largest lo with off[lo] <= i
#pragma unroll
        for (int s = 0; s < 13; ++s) {
            int mid = (lo + hi) >> 1;
            if (off[mid] <= i) lo = mid; else hi = mid;
        }
        unsigned pos = 0;
#pragma unroll
        for (int kk = 0; kk < NPASS; ++kk) {
            unsigned long long m = __ballot(k == kk);
            unsigned bc = (unsigned)__shfl((int)cur, kk, 64);
            if (k == kk) pos = bc + (unsigned)__popcll(m & mlt);
            if (lane == kk) cur += (unsigned)__popcll(m);
        }
        sp[pos] = (unsigned)hlo;
        atomicAdd(&cbag[((size_t)t * NPASS + k) * BATCH + lo], 1u);
    }
}

// ---------- 4) rowptr: per-(t,k) exclusive scan of per-bag counts ----------
__global__ void rowptr_kernel(const unsigned* __restrict__ cbag, const unsigned* __restrict__ bb,
                              unsigned* __restrict__ rowptr)
{
    int tk = blockIdx.x;                      // t*16 + k
    const unsigned* c = cbag + (size_t)tk * BATCH;
    unsigned* rp = rowptr + (size_t)tk * (BATCH + 1);
    __shared__ unsigned tsum[256];
    int tid = threadIdx.x;
    unsigned loc[32];
    unsigned s = 0;
#pragma unroll
    for (int e = 0; e < 32; ++e) { loc[e] = c[tid * 32 + e]; s += loc[e]; }
    tsum[tid] = s;
    __syncthreads();
    if (tid == 0) {
        unsigned run = 0;
        for (int j = 0; j < 256; ++j) { unsigned v = tsum[j]; tsum[j] = run; run += v; }
    }
    __syncthreads();
    unsigned run = bb[tk] + tsum[tid];
#pragma unroll
    for (int e = 0; e < 32; ++e) { rp[tid * 32 + e] = run; run += loc[e]; }
    if (tid == 255) rp[BATCH] = run;
}

// ---------- 5) PERSISTENT gather: 1024 blocks loop over 32 (pass, table-half)
// steps in lockstep. XCD-pinned via bid&7; per-XCD live window ~2.7MB < 4MB L2.
// Each thread: 2 independent bag chains per step (ILP 2), atomic-free stores. ----------
__global__ void gather_kernel(const float* __restrict__ W, const unsigned* __restrict__ sorted,
                              const unsigned* __restrict__ rowptr, float* __restrict__ partial)
{
    const int bid   = blockIdx.x;
    const int x     = bid & 7;          // xcd slot
    const int chunk = bid >> 3;         // 0..127 -> bags [chunk*64, chunk*64+64)
    const int task  = threadIdx.x & 7;
    const int slot  = threadIdx.x >> 3; // 0..31
    const int b0    = (chunk << 6) + slot;
    const int b1    = b0 + 32;

    for (int it = 0; it < NPASS * 2; ++it) {
        const int p  = it >> 1;
        const int tp = it & 1;
        const int t  = x + (tp << 3);

        const unsigned* rp = rowptr + (size_t)(t * NPASS + p) * (BATCH + 1);
        unsigned a0 = rp[b0], a1 = rp[b0 + 1];
        unsigned c0 = rp[b1], c1 = rp[b1 + 1];

        const unsigned* sp = sorted + (size_t)t * SORT_STRIDE;
        const float* Wt = W + ((size_t)task * NUM_TABLES + t) * HASH + (size_t)p * RANGE;

        float acc0 = 0.0f, acc1 = 0.0f;
        for (unsigned u = a0; u < a1; ++u) acc0 += Wt[sp[u]];
        for (unsigned u = c0; u < c1; ++u) acc1 += Wt[sp[u]];

        float* pb = partial + ((size_t)p * NUM_TABLES + t) * (BATCH * 8) + task;
        pb[(size_t)b0 * 8] = acc0;
        pb[(size_t)b1 * 8] = acc1;
    }
}

// ---------- 6) reduce 16 passes ----------
__global__ void reduce_kernel(const float* __restrict__ partial, float* __restrict__ out)
{
    int tid  = blockIdx.x * blockDim.x + threadIdx.x;   // 65536 threads
    int task = tid & 7;
    int b    = tid >> 3;

    float s[NUM_TABLES];
#pragma unroll
    for (int t = 0; t < NUM_TABLES; ++t) s[t] = 0.0f;

    for (int p = 0; p < NPASS; ++p) {
#pragma unroll
        for (int t = 0; t < NUM_TABLES; ++t) {
            s[t] += partial[((((size_t)p * NUM_TABLES + t) * BATCH + b) << 3) + task];
        }
    }

    float4* o = (float4*)(out + ((size_t)task * BATCH + b) * NUM_TABLES);
    o[0] = make_float4(s[0],  s[1],  s[2],  s[3]);
    o[1] = make_float4(s[4],  s[5],  s[6],  s[7]);
    o[2] = make_float4(s[8],  s[9],  s[10], s[11]);
    o[3] = make_float4(s[12], s[13], s[14], s[15]);
}

// ---------- fallback (round-3 kernel) if ws is too small ----------
__global__ void pool_fallback_kernel(const float* __restrict__ W, const int* __restrict__ offsets,
                                     const int* __restrict__ indices, float* __restrict__ out)
{
    const int block = blockIdx.x;
    const int t        = block >> 11;
    const int bag_base = (block & 2047) << 2;
    const int wave     = threadIdx.x >> 6;
    const int b        = bag_base + wave;
    const int lane     = threadIdx.x & 63;
    const int task     = lane & 7;
    const int split    = lane >> 3;
    const int start = offsets[t * OFF_ROW + b];
    const int end   = offsets[t * OFF_ROW + b + 1];
    const int*   idxp   = indices + (size_t)t * NNZ;
    const float* Wslice = W + ((size_t)task * NUM_TABLES + t) * (size_t)HASH;
    float acc = 0.0f;
    for (int i = start + split; i < end; i += 8) acc += Wslice[idxp[i]];
    acc += __shfl_xor(acc, 8); acc += __shfl_xor(acc, 16); acc += __shfl_xor(acc, 32);
    if (split == 0) out[((size_t)task * BATCH + b) * NUM_TABLES + t] = acc;
}

extern "C" void kernel_launch(void* const* d_in, const int* in_sizes, int n_in,
                              void* d_out, int out_size, void* d_ws, size_t ws_size,
                              hipStream_t stream) {
    const float* W       = (const float*)d_in[0];
    const int*   offsets = (const int*)d_in[1];
    const int*   indices = (const int*)d_in[2];
    float*       out     = (float*)d_out;

    if (ws_size < WS_NEED) {
        pool_fallback_kernel<<<NUM_TABLES * 2048, 256, 0, stream>>>(W, offsets, indices, out);
        return;
    }

    unsigned* hist    = (unsigned*)((char*)d_ws + WS_HIST);
    unsigned* bb      = (unsigned*)((char*)d_ws + WS_BB);
    unsigned* cntb    = (unsigned*)((char*)d_ws + WS_CNTB);
    unsigned* cbag    = (unsigned*)((char*)d_ws + WS_CBAG);
    unsigned* rowptr  = (unsigned*)((char*)d_ws + WS_RP);
    unsigned* sorted  = (unsigned*)((char*)d_ws + WS_SORT);
    float*    partial = (float*)((char*)d_ws + WS_PART);

    hist_kernel<<<(NUM_TABLES * NCHUNK) / 4, 256, 0, stream>>>(indices, hist, (uint4*)cbag);
    scan_kernel<<<NUM_TABLES, 64, 0, stream>>>(hist, bb, cntb);
    scatter_kernel<<<(NUM_TABLES * NCHUNK) / 4, 256, 0, stream>>>(indices, offsets, hist, bb, sorted, cbag);
    rowptr_kernel<<<NUM_TABLES * NPASS, 256, 0, stream>>>(cbag, bb, rowptr);
    gather_kernel<<<1024, 256, 0, stream>>>(W, sorted, rowptr, partial);
    reduce_kernel<<<(NUM_TASKS * BATCH) / 256, 256, 0, stream>>>(partial, out);
}

// Round 9
// 371.577 us; speedup vs baseline: 1.4245x; 1.4245x over previous
//
#include <hip/hip_runtime.h>

#define NUM_TASKS 8
#define NUM_TABLES 16
#define HASH 1000000
#define BATCH 8192
#define NNZ (BATCH * 20)
#define OFF_ROW (BATCH + 1)
#define NPASS 16
#define RANGE (HASH / NPASS)        // 62500 floats = 15625 float4 per (task,t) window
#define CHUNK 640
#define NCHUNK (NNZ / CHUNK)        // 256
#define SORT_STRIDE (NNZ + 512)
#define NGROUP (NPASS * 2)          // 32 (pass, table-half) groups
#define PF_BLOCKS 256               // prefetcher blocks per group (32 per XCD)
#define GA_BLOCKS 2048              // gather blocks per group (256 per XCD)
#define GRP_BLOCKS (PF_BLOCKS + GA_BLOCKS)   // 2304
#define WQ 3907                     // ceil(15625/4) float4 per prefetch slice

// ws layout (bytes). hist/bb/cbag live INSIDE the partial region but are dead
// before gather (the only writer of partial) runs — safe aliasing.
#define WS_PART  0ull                                   // [16p][16t][8192b][8task] f32 = 64 MB
#define WS_HIST  0ull                                   // [16t][16k][256c] u32 = 256 KB
#define WS_BB    262144ull                              // [16t][16k] u32
#define WS_CNTB  263168ull                              // [16t][16k] u32
#define WS_CBAG  (1ull << 20)                           // [16t][16k][8192b] u32 = 8 MB
#define PART_BYTES ((size_t)NPASS * NUM_TABLES * BATCH * NUM_TASKS * 4)   // 67,108,864
#define WS_RP    PART_BYTES                             // [16t][16k][8193] u32 = 8.39 MB
#define RP_BYTES ((size_t)NUM_TABLES * NPASS * (BATCH + 1) * 4)
#define WS_SORT  (WS_RP + RP_BYTES)                     // [16t][SORT_STRIDE] u32 = 10.5 MB
#define WS_NEED  (WS_SORT + (size_t)NUM_TABLES * SORT_STRIDE * 4)         // ~86 MB

// ---------- 1) per-chunk histogram + zero cbag ----------
__global__ void hist_kernel(const int* __restrict__ indices, unsigned* __restrict__ hist,
                            uint4* __restrict__ cbag_v)   // 524288 uint4 = 8 MB
{
    int zt = blockIdx.x * blockDim.x + threadIdx.x;
    uint4 z = make_uint4(0u, 0u, 0u, 0u);
    cbag_v[zt * 2]     = z;
    cbag_v[zt * 2 + 1] = z;

    __shared__ int h[4][NPASS];
    int w = threadIdx.x >> 6, lane = threadIdx.x & 63;
    int g = blockIdx.x * 4 + w;
    int t = g >> 8, chunk = g & 255;
    if (lane < NPASS) h[w][lane] = 0;
    __syncthreads();
    const int* ip = indices + (size_t)t * NNZ + chunk * CHUNK;
    for (int r = 0; r < CHUNK / 64; ++r) {
        int k = ip[r * 64 + lane] / RANGE;
        atomicAdd(&h[w][k], 1);
    }
    __syncthreads();
    if (lane < NPASS) hist[((size_t)t * NPASS + lane) * NCHUNK + chunk] = (unsigned)h[w][lane];
}

// ---------- 2) scan: per-(t,k) exclusive chunk scan + 32-aligned bucket bases ----------
__global__ void scan_kernel(unsigned* __restrict__ hist, unsigned* __restrict__ bb, unsigned* __restrict__ cnt)
{
    int t = blockIdx.x, tid = threadIdx.x;
    __shared__ unsigned tot[NPASS];
    if (tid < NPASS) {
        unsigned run = 0;
        unsigned* hp = hist + ((size_t)t * NPASS + tid) * NCHUNK;
        for (int c = 0; c < NCHUNK; ++c) { unsigned v = hp[c]; hp[c] = run; run += v; }
        tot[tid] = run;
        cnt[t * NPASS + tid] = run;
    }
    __syncthreads();
    if (tid == 0) {
        unsigned base = 0;
        for (int k = 0; k < NPASS; ++k) { bb[t * NPASS + k] = base; base += (tot[k] + 31u) & ~31u; }
    }
}

// ---------- 3) stable scatter + per-(t,k,bag) counts ----------
__global__ void scatter_kernel(const int* __restrict__ indices, const int* __restrict__ offsets,
                               const unsigned* __restrict__ hist, const unsigned* __restrict__ bb,
                               unsigned* __restrict__ sorted, unsigned* __restrict__ cbag)
{
    int w = threadIdx.x >> 6, lane = threadIdx.x & 63;
    int g = blockIdx.x * 4 + w;
    int t = g >> 8, chunk = g & 255;
    unsigned cur = 0;
    if (lane < NPASS)
        cur = bb[t * NPASS + lane] + hist[((size_t)t * NPASS + lane) * NCHUNK + chunk];
    unsigned long long mlt = (1ull << lane) - 1ull;
    const int* off = offsets + t * OFF_ROW;
    const int* ip  = indices + (size_t)t * NNZ;
    unsigned* sp   = sorted + (size_t)t * SORT_STRIDE;

    for (int r = 0; r < CHUNK / 64; ++r) {
        int i = chunk * CHUNK + r * 64 + lane;
        int raw = ip[i];
        int k   = raw / RANGE;
        int hlo = raw - k * RANGE;
        int lo = 0, hi = BATCH;                 // bag: largest lo with off[lo] <= i
#pragma unroll
        for (int s = 0; s < 13; ++s) {
            int mid = (lo + hi) >> 1;
            if (off[mid] <= i) lo = mid; else hi = mid;
        }
        unsigned pos = 0;
#pragma unroll
        for (int kk = 0; kk < NPASS; ++kk) {
            unsigned long long m = __ballot(k == kk);
            unsigned bc = (unsigned)__shfl((int)cur, kk, 64);
            if (k == kk) pos = bc + (unsigned)__popcll(m & mlt);
            if (lane == kk) cur += (unsigned)__popcll(m);
        }
        sp[pos] = (unsigned)hlo;
        atomicAdd(&cbag[((size_t)t * NPASS + k) * BATCH + lo], 1u);
    }
}

// ---------- 4) rowptr: per-(t,k) exclusive scan of per-bag counts ----------
__global__ void rowptr_kernel(const unsigned* __restrict__ cbag, const unsigned* __restrict__ bb,
                              unsigned* __restrict__ rowptr)
{
    int tk = blockIdx.x;                      // t*16 + k
    const unsigned* c = cbag + (size_t)tk * BATCH;
    unsigned* rp = rowptr + (size_t)tk * (BATCH + 1);
    __shared__ unsigned tsum[256];
    int tid = threadIdx.x;
    unsigned loc[32];
    unsigned s = 0;
#pragma unroll
    for (int e = 0; e < 32; ++e) { loc[e] = c[tid * 32 + e]; s += loc[e]; }
    tsum[tid] = s;
    __syncthreads();
    if (tid == 0) {
        unsigned run = 0;
        for (int j = 0; j < 256; ++j) { unsigned v = tsum[j]; tsum[j] = run; run += v; }
    }
    __syncthreads();
    unsigned run = bb[tk] + tsum[tid];
#pragma unroll
    for (int e = 0; e < 32; ++e) { rp[tid * 32 + e] = run; run += loc[e]; }
    if (tid == 255) rp[BATCH] = run;
}

// ---------- 5) gather with software-pipelined L2 window streaming ----------
// Groups of 2304 blocks per (pass, table-half), dispatched in bid order:
//   [ 256 prefetchers for group g+1 | 2048 gather blocks for group g ]
// plus a 256-block prologue prefetching group 0. Prefetchers stream the next
// window (2 MB/XCD, coalesced float4) into their XCD's L2 one group-duration
// ahead; gathers then hit L2 instead of doing random HBM line fetches
// (random 64B HBM ≈ 2.2 TB/s vs sequential 6.3 TB/s — that gap was the
// round-6 gather's 265 us). L2 holds window(g)+window(g+1) = 4 MB exactly.
__global__ void gather_kernel(const float* __restrict__ W, const unsigned* __restrict__ sorted,
                              const unsigned* __restrict__ rowptr, float* __restrict__ partial)
{
    int bid = blockIdx.x;
    int g, r;
    if (bid < PF_BLOCKS) { g = -1; r = bid; }
    else { g = (bid - PF_BLOCKS) / GRP_BLOCKS; r = (bid - PF_BLOCKS) % GRP_BLOCKS; }

    if (g < 0 || r < PF_BLOCKS) {
        // ---- prefetch window of group pg = g+1 into this XCD's L2 ----
        int pg = g + 1;
        if (pg >= NGROUP) return;
        int x = r & 7;                       // xcd slot (bid & 7 == r & 7)
        int s = r >> 3;                      // 0..31: slice = (task, quarter)
        int task = s >> 2, q = s & 3;
        int p = pg >> 1, tp = pg & 1;
        int t = x + (tp << 3);
        const float4* wv = (const float4*)(W + ((size_t)task * NUM_TABLES + t) * HASH
                                             + (size_t)p * RANGE);
        int lo = q * WQ, hi = min(RANGE / 4, lo + WQ);
        for (int u = lo + (int)threadIdx.x; u < hi; u += 256) {
            float4 v = wv[u];
            asm volatile("" :: "v"(v.x), "v"(v.y), "v"(v.z), "v"(v.w));  // sink, keep load
        }
        return;
    }

    // ---- gather for group g (round-6 proven shape) ----
    r -= PF_BLOCKS;
    int x   = r & 7;
    int blk = r >> 3;                        // 0..255
    int p = g >> 1, tp = g & 1;
    int t = x + (tp << 3);
    int task = threadIdx.x & 7;
    int b = (blk << 5) + ((int)threadIdx.x >> 3);

    const unsigned* rp = rowptr + (size_t)(t * NPASS + p) * (BATCH + 1);
    unsigned s0 = rp[b], s1 = rp[b + 1];
    const unsigned* sp = sorted + (size_t)t * SORT_STRIDE;
    const float* Wt = W + ((size_t)task * NUM_TABLES + t) * HASH + (size_t)p * RANGE;

    float acc = 0.0f;
    for (unsigned u = s0; u < s1; ++u) acc += Wt[sp[u]];

    partial[(((size_t)p * NUM_TABLES + t) * BATCH + b) * 8 + task] = acc;
}

// ---------- 6) reduce 16 passes ----------
__global__ void reduce_kernel(const float* __restrict__ partial, float* __restrict__ out)
{
    int tid  = blockIdx.x * blockDim.x + threadIdx.x;   // 65536 threads
    int task = tid & 7;
    int b    = tid >> 3;

    float s[NUM_TABLES];
#pragma unroll
    for (int t = 0; t < NUM_TABLES; ++t) s[t] = 0.0f;

    for (int p = 0; p < NPASS; ++p) {
#pragma unroll
        for (int t = 0; t < NUM_TABLES; ++t) {
            s[t] += partial[((((size_t)p * NUM_TABLES + t) * BATCH + b) << 3) + task];
        }
    }

    float4* o = (float4*)(out + ((size_t)task * BATCH + b) * NUM_TABLES);
    o[0] = make_float4(s[0],  s[1],  s[2],  s[3]);
    o[1] = make_float4(s[4],  s[5],  s[6],  s[7]);
    o[2] = make_float4(s[8],  s[9],  s[10], s[11]);
    o[3] = make_float4(s[12], s[13], s[14], s[15]);
}

// ---------- fallback (round-3 kernel) if ws is too small ----------
__global__ void pool_fallback_kernel(const float* __restrict__ W, const int* __restrict__ offsets,
                                     const int* __restrict__ indices, float* __restrict__ out)
{
    const int block = blockIdx.x;
    const int t        = block >> 11;
    const int bag_base = (block & 2047) << 2;
    const int wave     = threadIdx.x >> 6;
    const int b        = bag_base + wave;
    const int lane     = threadIdx.x & 63;
    const int task     = lane & 7;
    const int split    = lane >> 3;
    const int start = offsets[t * OFF_ROW + b];
    const int end   = offsets[t * OFF_ROW + b + 1];
    const int*   idxp   = indices + (size_t)t * NNZ;
    const float* Wslice = W + ((size_t)task * NUM_TABLES + t) * (size_t)HASH;
    float acc = 0.0f;
    for (int i = start + split; i < end; i += 8) acc += Wslice[idxp[i]];
    acc += __shfl_xor(acc, 8); acc += __shfl_xor(acc, 16); acc += __shfl_xor(acc, 32);
    if (split == 0) out[((size_t)task * BATCH + b) * NUM_TABLES + t] = acc;
}

extern "C" void kernel_launch(void* const* d_in, const int* in_sizes, int n_in,
                              void* d_out, int out_size, void* d_ws, size_t ws_size,
                              hipStream_t stream) {
    const float* W       = (const float*)d_in[0];
    const int*   offsets = (const int*)d_in[1];
    const int*   indices = (const int*)d_in[2];
    float*       out     = (float*)d_out;

    if (ws_size < WS_NEED) {
        pool_fallback_kernel<<<NUM_TABLES * 2048, 256, 0, stream>>>(W, offsets, indices, out);
        return;
    }

    unsigned* hist    = (unsigned*)((char*)d_ws + WS_HIST);
    unsigned* bb      = (unsigned*)((char*)d_ws + WS_BB);
    unsigned* cntb    = (unsigned*)((char*)d_ws + WS_CNTB);
    unsigned* cbag    = (unsigned*)((char*)d_ws + WS_CBAG);
    unsigned* rowptr  = (unsigned*)((char*)d_ws + WS_RP);
    unsigned* sorted  = (unsigned*)((char*)d_ws + WS_SORT);
    float*    partial = (float*)((char*)d_ws + WS_PART);

    hist_kernel<<<(NUM_TABLES * NCHUNK) / 4, 256, 0, stream>>>(indices, hist, (uint4*)cbag);
    scan_kernel<<<NUM_TABLES, 64, 0, stream>>>(hist, bb, cntb);
    scatter_kernel<<<(NUM_TABLES * NCHUNK) / 4, 256, 0, stream>>>(indices, offsets, hist, bb, sorted, cbag);
    rowptr_kernel<<<NUM_TABLES * NPASS, 256, 0, stream>>>(cbag, bb, rowptr);
    gather_kernel<<<PF_BLOCKS + NGROUP * GRP_BLOCKS, 256, 0, stream>>>(W, sorted, rowptr, partial);
    reduce_kernel<<<(NUM_TASKS * BATCH) / 256, 256, 0, stream>>>(partial, out);
}